// Round 5
// baseline (848.451 us; speedup 1.0000x reference)
//
#include <hip/hip_runtime.h>
#include <stdint.h>
#include <stddef.h>

#define D0 4096
#define D1 1024
#define NOUT 1000
#define NB 64

#define NCH0 2
#define CHSH0 11
#define NBK0 (33 * NCH0)        // 66
#define PSTRIDE0 4352           // >= 4096 + 66*3, multiple of 4
#define SENT0 (4096u << 14)     // byte offset of zero row in w0T

#define NCH2 4
#define CHSH2 8
#define NBK2 (33 * NCH2)        // 132
#define PSTRIDE2 1472           // >= 1024 + 132*3, multiple of 4
#define SENT2 (1024u << 12)     // byte offset of zero row in w2T

// ---------------------------------------------------------------------------
// Spike pattern for uniform spike coding, N in [0,32] -> 32-bit cycle mask.
// Matches jnp: spacing = 32.f/N (fp32), spike at c iff fmod(c, spacing) < 1.
// floor(c/spacing) < N always true for 0<N<32 (margin >= N/32 >> fp eps).
// ---------------------------------------------------------------------------
__device__ __forceinline__ uint32_t spike_pattern(int N) {
  if (N <= 0) return 0u;
  if (N >= 32) return 0xFFFFFFFFu;
  float spacing = 32.0f / (float)N;
  uint32_t m = 0;
  for (int c = 0; c < 32; ++c) {
    if (fmodf((float)c, spacing) < 1.0f) m |= (1u << c);
  }
  return m;
}

// ---------------------------------------------------------------------------
// Fused prep:
//  blocks [0,64):   per-batch counting sort of core-0 inputs by key =
//                   33*chunk + N (chunk = j>>11). Buckets padded to x4 with
//                   sentinel entries (zero-row byte offset) so every segment
//                   is 4-aligned & 4-sized; perm values prescaled to byte
//                   offsets (j<<14). Sentinel adds exact +0.0 -> bit-identical.
//  block 64:        inverse output index + zero rows for w0T/w2T sentinels.
//  next 16384:      w0 transpose tiles -> w0T[j][o].
//  last 1024:       w2 transpose tiles -> w2T[j][o] (o >= 1000 zero-padded).
// Within-bucket order is atomic-nondeterministic: perturbs fp64 bucket sums
// only at ~1e-16 (absmax stayed 0 across R1-R4 with this property).
// ---------------------------------------------------------------------------
__global__ void prep_k(const float* __restrict__ w0, const float* __restrict__ w2,
                       const float* __restrict__ x, const int* __restrict__ idx0,
                       const int* __restrict__ idx_out,
                       float* __restrict__ w0T, float* __restrict__ w2T,
                       uint32_t* __restrict__ perm0, int* __restrict__ starts0,
                       int* __restrict__ inv) {
  __shared__ int keys[D0];
  __shared__ int hist[NBK0];
  __shared__ int base[NBK0 + 1];
  __shared__ int cursor[NBK0];
  __shared__ float tile[32][33];
  int bid = blockIdx.x;
  int tid = threadIdx.x;
  if (bid < NB) {
    int b = bid;
    for (int k = tid; k < NBK0; k += 256) hist[k] = 0;
    __syncthreads();
    for (int j = tid; j < D0; j += 256) {
      int N = (int)rintf(x[(size_t)b * D0 + idx0[j]] * 32.0f);  // round-half-even
      int k = (j >> CHSH0) * 33 + N;
      keys[j] = k;
      atomicAdd(&hist[k], 1);
    }
    __syncthreads();
    if (tid == 0) {
      int s = 0;
      for (int k = 0; k < NBK0; ++k) {
        base[k] = s; cursor[k] = s;
        s += hist[k];
        s = (s + 3) & ~3;           // pad bucket to multiple of 4
      }
      base[NBK0] = s;
    }
    __syncthreads();
    for (int k = tid; k <= NBK0; k += 256) starts0[b * (NBK0 + 1) + k] = base[k];
    uint32_t* pb = perm0 + (size_t)b * PSTRIDE0;
    for (int i = tid; i < PSTRIDE0; i += 256) pb[i] = SENT0;
    __syncthreads();
    for (int j = tid; j < D0; j += 256) {
      int pos = atomicAdd(&cursor[keys[j]], 1);
      pb[pos] = (uint32_t)j << 14;  // prescaled byte offset into w0T
    }
  } else if (bid == NB) {
    for (int o = tid; o < D1; o += 256) inv[o] = -1;
    __syncthreads();
    for (int r = tid; r < NOUT; r += 256) inv[idx_out[r]] = r;
    // sentinel zero rows
    float* zr0 = w0T + (size_t)D0 * D0;
    for (int i = tid; i < D0; i += 256) zr0[i] = 0.0f;
    float* zr2 = w2T + (size_t)D1 * D1;
    for (int i = tid; i < D1; i += 256) zr2[i] = 0.0f;
  } else if (bid < NB + 1 + 16384) {
    int tb = bid - (NB + 1);
    int j0 = (tb & 127) * 32;
    int o0 = (tb >> 7) * 32;
    int tx = tid & 31, ty = tid >> 5;
    for (int r = ty; r < 32; r += 8)
      tile[r][tx] = w0[(size_t)(o0 + r) * D0 + j0 + tx];
    __syncthreads();
    for (int r = ty; r < 32; r += 8)
      w0T[(size_t)(j0 + r) * D0 + o0 + tx] = tile[tx][r];
  } else {
    int tb = bid - (NB + 1 + 16384);
    int j0 = (tb & 31) * 32;
    int o0 = (tb >> 5) * 32;
    int tx = tid & 31, ty = tid >> 5;
    for (int r = ty; r < 32; r += 8) {
      int o = o0 + r;
      tile[r][tx] = (o < NOUT) ? w2[(size_t)o * D1 + j0 + tx] : 0.0f;
    }
    __syncthreads();
    for (int r = ty; r < 32; r += 8)
      w2T[(size_t)(j0 + r) * D1 + o0 + tx] = tile[tx][r];
  }
}

// ---------------------------------------------------------------------------
// Core-0 LIF, fp64-exact, no atomics. Thread = one o for batch b; sweeps the
// 2 j-chunks in-block (all blocks in the same order -> per-XCD wt footprint
// = 2 o-tiles x 2 MB = 4 MB, L2-resident, ~43 MB compulsory HBM fetch).
// Segments are 4-aligned/4-sized (sentinel-padded) -> inner loop is pure
// uint4 perm loads (broadcast) + 8 gathers in flight; gather address is
// uniform prescaled byte offset + o*4 (one v_add_u32, saddr-form load).
// Epilogue: pattern-scatter bsum -> contrib, then 32-step membrane scan.
// ---------------------------------------------------------------------------
__launch_bounds__(256, 4)
__global__ void lif0_k(const float* __restrict__ wt, const uint32_t* __restrict__ perm,
                       const int* __restrict__ starts, const float* __restrict__ thr_p,
                       int* __restrict__ cnt_out) {
  __shared__ uint32_t pat[33];
  __shared__ int stL[NBK0 + 1];
  int tid = threadIdx.x;
  int o = blockIdx.x * 256 + tid;
  int b = blockIdx.y;
  if (tid < 33) pat[tid] = spike_pattern(tid);
  if (tid < NBK0 + 1) stL[tid] = starts[b * (NBK0 + 1) + tid];
  __syncthreads();

  const char* wtc = (const char*)wt;
  uint32_t o4 = (uint32_t)o * 4u;

  double bsum[32];
#pragma unroll
  for (int k = 0; k < 32; ++k) bsum[k] = 0.0;

  const uint32_t* permb = perm + (size_t)b * PSTRIDE0;

  for (int ch = 0; ch < NCH0; ++ch) {
#pragma unroll 1
    for (int kl = 1; kl <= 32; ++kl) {
      int seg = ch * 33 + kl;
      int s = stL[seg], e = stL[seg + 1];
      if (s == e) continue;  // uniform branch
      double a0 = 0.0, a1 = 0.0, a2 = 0.0, a3 = 0.0;
      int i = s;
      for (; i + 8 <= e; i += 8) {
        uint4 p0 = *(const uint4*)(permb + i);
        uint4 p1 = *(const uint4*)(permb + i + 4);
        float f0 = *(const float*)(wtc + (uint32_t)(p0.x + o4));
        float f1 = *(const float*)(wtc + (uint32_t)(p0.y + o4));
        float f2 = *(const float*)(wtc + (uint32_t)(p0.z + o4));
        float f3 = *(const float*)(wtc + (uint32_t)(p0.w + o4));
        float f4 = *(const float*)(wtc + (uint32_t)(p1.x + o4));
        float f5 = *(const float*)(wtc + (uint32_t)(p1.y + o4));
        float f6 = *(const float*)(wtc + (uint32_t)(p1.z + o4));
        float f7 = *(const float*)(wtc + (uint32_t)(p1.w + o4));
        a0 += (double)f0; a1 += (double)f1; a2 += (double)f2; a3 += (double)f3;
        a0 += (double)f4; a1 += (double)f5; a2 += (double)f6; a3 += (double)f7;
      }
      if (i < e) {  // exactly 4 (segments are multiples of 4)
        uint4 p0 = *(const uint4*)(permb + i);
        float f0 = *(const float*)(wtc + (uint32_t)(p0.x + o4));
        float f1 = *(const float*)(wtc + (uint32_t)(p0.y + o4));
        float f2 = *(const float*)(wtc + (uint32_t)(p0.z + o4));
        float f3 = *(const float*)(wtc + (uint32_t)(p0.w + o4));
        a0 += (double)f0; a1 += (double)f1; a2 += (double)f2; a3 += (double)f3;
      }
      bsum[kl - 1] += (a0 + a1) + (a2 + a3);
    }
  }

  double contrib[32];
#pragma unroll
  for (int t = 0; t < 32; ++t) contrib[t] = 0.0;
#pragma unroll
  for (int k = 1; k <= 32; ++k) {
    uint32_t m = pat[k];
    double v = bsum[k - 1];
#pragma unroll
    for (int t = 0; t < 32; ++t)
      contrib[t] += ((m >> t) & 1u) ? v : 0.0;
  }

  double th = (double)thr_p[0];
  double memb = 0.0;
  int cnt = 0;
#pragma unroll
  for (int t = 0; t < 32; ++t) {
    memb += contrib[t];
    if (memb > th) { memb -= th; ++cnt; }  // strict: threshold < memb
  }
  cnt_out[(size_t)b * D0 + o] = cnt;
}

// ---------------------------------------------------------------------------
// Core-2 prep: avg_pool2d on exact spike counts -> N1 = rint(cnt4/4) (exact:
// sums/divisions by pow2 of multiples of 1/32 are exact in fp32; clip no-op),
// then padded counting sort, key = 33*(j>>8) + N1[idx2[j]], perm prescaled
// (j<<12), sentinel = zero row of w2T.
// ---------------------------------------------------------------------------
__global__ void pool_sort_k(const int* __restrict__ k0, const int* __restrict__ idx1,
                            const int* __restrict__ idx2,
                            uint32_t* __restrict__ perm, int* __restrict__ starts) {
  __shared__ int Nls[D1];
  __shared__ int keys[D1];
  __shared__ int hist[NBK2];
  __shared__ int base[NBK2 + 1];
  __shared__ int cursor[NBK2];
  int b = blockIdx.x, tid = threadIdx.x;
  for (int k = tid; k < NBK2; k += 256) hist[k] = 0;
  for (int i = tid; i < D1; i += 256) {
    int c = i >> 4, h2 = (i >> 2) & 3, w2v = i & 3;
    int cnt = 0;
#pragma unroll
    for (int dh = 0; dh < 2; ++dh)
#pragma unroll
      for (int dw = 0; dw < 2; ++dw) {
        int q = c * 64 + (2 * h2 + dh) * 8 + (2 * w2v + dw);
        cnt += k0[(size_t)b * D0 + idx1[q]];
      }
    Nls[i] = (int)rintf((float)cnt * 0.25f);
  }
  __syncthreads();
  for (int j = tid; j < D1; j += 256) {
    int k = (j >> CHSH2) * 33 + Nls[idx2[j]];
    keys[j] = k;
    atomicAdd(&hist[k], 1);
  }
  __syncthreads();
  if (tid == 0) {
    int s = 0;
    for (int k = 0; k < NBK2; ++k) {
      base[k] = s; cursor[k] = s;
      s += hist[k];
      s = (s + 3) & ~3;
    }
    base[NBK2] = s;
  }
  __syncthreads();
  for (int k = tid; k <= NBK2; k += 256) starts[b * (NBK2 + 1) + k] = base[k];
  uint32_t* pb = perm + (size_t)b * PSTRIDE2;
  for (int i = tid; i < PSTRIDE2; i += 256) pb[i] = SENT2;
  __syncthreads();
  for (int j = tid; j < D1; j += 256) {
    int pos = atomicAdd(&cursor[keys[j]], 1);
    pb[pos] = (uint32_t)j << 12;
  }
}

// ---------------------------------------------------------------------------
// Core-2 LIF: block = 64 o's x 4 j-chunk waves (grid (16,64) -> 4 blocks/CU,
// 4 waves/SIMD machine-wide). Each thread: bucket sums over its chunk ->
// contrib[32] -> fp64 LDS combine across chunks -> wave-0 membrane scan ->
// output write via inverse index. w2T (4 MB) is L2-resident everywhere.
// LDS-atomic combine order perturbs sums only at ~1e-16.
// ---------------------------------------------------------------------------
__launch_bounds__(256, 4)
__global__ void lif2_k(const float* __restrict__ wt, const uint32_t* __restrict__ perm,
                       const int* __restrict__ starts, const float* __restrict__ thr_p,
                       const int* __restrict__ inv, float* __restrict__ out) {
  __shared__ uint32_t pat[33];
  __shared__ int stL[NBK2 + 1];
  __shared__ double cLDS[64][33];
  int tid = threadIdx.x;
  int b = blockIdx.y;
  int o_local = tid & 63;
  int ch = tid >> 6;
  int o = blockIdx.x * 64 + o_local;
  if (tid < 33) pat[tid] = spike_pattern(tid);
  for (int k = tid; k < NBK2 + 1; k += 256) stL[k] = starts[b * (NBK2 + 1) + k];
  for (int i = tid; i < 64 * 33; i += 256) (&cLDS[0][0])[i] = 0.0;
  __syncthreads();

  const char* wtc = (const char*)wt;
  uint32_t o4 = (uint32_t)o * 4u;

  double bsum[32];
#pragma unroll
  for (int k = 0; k < 32; ++k) bsum[k] = 0.0;

  const uint32_t* permb = perm + (size_t)b * PSTRIDE2;

#pragma unroll 1
  for (int kl = 1; kl <= 32; ++kl) {
    int seg = ch * 33 + kl;
    int s = stL[seg], e = stL[seg + 1];
    if (s == e) continue;  // wave-uniform branch
    double a0 = 0.0, a1 = 0.0, a2 = 0.0, a3 = 0.0;
    int i = s;
    for (; i + 8 <= e; i += 8) {
      uint4 p0 = *(const uint4*)(permb + i);
      uint4 p1 = *(const uint4*)(permb + i + 4);
      float f0 = *(const float*)(wtc + (uint32_t)(p0.x + o4));
      float f1 = *(const float*)(wtc + (uint32_t)(p0.y + o4));
      float f2 = *(const float*)(wtc + (uint32_t)(p0.z + o4));
      float f3 = *(const float*)(wtc + (uint32_t)(p0.w + o4));
      float f4 = *(const float*)(wtc + (uint32_t)(p1.x + o4));
      float f5 = *(const float*)(wtc + (uint32_t)(p1.y + o4));
      float f6 = *(const float*)(wtc + (uint32_t)(p1.z + o4));
      float f7 = *(const float*)(wtc + (uint32_t)(p1.w + o4));
      a0 += (double)f0; a1 += (double)f1; a2 += (double)f2; a3 += (double)f3;
      a0 += (double)f4; a1 += (double)f5; a2 += (double)f6; a3 += (double)f7;
    }
    if (i < e) {
      uint4 p0 = *(const uint4*)(permb + i);
      float f0 = *(const float*)(wtc + (uint32_t)(p0.x + o4));
      float f1 = *(const float*)(wtc + (uint32_t)(p0.y + o4));
      float f2 = *(const float*)(wtc + (uint32_t)(p0.z + o4));
      float f3 = *(const float*)(wtc + (uint32_t)(p0.w + o4));
      a0 += (double)f0; a1 += (double)f1; a2 += (double)f2; a3 += (double)f3;
    }
    bsum[kl - 1] += (a0 + a1) + (a2 + a3);
  }

  // pattern-scatter, then combine across chunks in LDS
#pragma unroll
  for (int t = 0; t < 32; ++t) {
    double c = 0.0;
#pragma unroll
    for (int k = 1; k <= 32; ++k)
      c += ((pat[k] >> t) & 1u) ? bsum[k - 1] : 0.0;
    unsafeAtomicAdd(&cLDS[o_local][t], c);
  }
  __syncthreads();

  if (tid < 64) {
    double th = (double)thr_p[0];
    double memb = 0.0;
    int cnt = 0;
#pragma unroll
    for (int t = 0; t < 32; ++t) {
      memb += cLDS[tid][t];
      if (memb > th) { memb -= th; ++cnt; }
    }
    int r = inv[o];
    if (r >= 0) out[(size_t)b * NOUT + r] = (float)cnt;
  }
}

// ---------------------------------------------------------------------------
extern "C" void kernel_launch(void* const* d_in, const int* in_sizes, int n_in,
                              void* d_out, int out_size, void* d_ws, size_t ws_size,
                              hipStream_t stream) {
  const float* x      = (const float*)d_in[0];
  const float* w0     = (const float*)d_in[1];
  const float* t0     = (const float*)d_in[2];
  const float* w2     = (const float*)d_in[3];
  const float* t2     = (const float*)d_in[4];
  const int*   idx0   = (const int*)d_in[5];
  const int*   idx1   = (const int*)d_in[6];
  const int*   idx2   = (const int*)d_in[7];
  const int*   idx_out= (const int*)d_in[8];
  float* out = (float*)d_out;

  char* ws = (char*)d_ws;
  float*    w0T     = (float*)ws;    ws += (size_t)(D0 + 1) * D0 * 4;  // +sentinel row
  float*    w2T     = (float*)ws;    ws += (size_t)(D1 + 1) * D1 * 4;  // +sentinel row
  uint32_t* perm0   = (uint32_t*)ws; ws += (size_t)NB * PSTRIDE0 * 4;
  uint32_t* perm2   = (uint32_t*)ws; ws += (size_t)NB * PSTRIDE2 * 4;
  int*      k0      = (int*)ws;      ws += (size_t)NB * D0 * 4;
  int*      starts0 = (int*)ws;      ws += (size_t)NB * (NBK0 + 1) * 4;
  int*      starts2 = (int*)ws;      ws += (size_t)NB * (NBK2 + 1) * 4;
  int*      inv     = (int*)ws;      ws += (size_t)D1 * 4;

  prep_k<<<NB + 1 + 16384 + 1024, 256, 0, stream>>>(w0, w2, x, idx0, idx_out,
                                                    w0T, w2T, perm0, starts0, inv);
  lif0_k<<<dim3(D0 / 256, NB), 256, 0, stream>>>(w0T, perm0, starts0, t0, k0);
  pool_sort_k<<<NB, 256, 0, stream>>>(k0, idx1, idx2, perm2, starts2);
  lif2_k<<<dim3(D1 / 64, NB), 256, 0, stream>>>(w2T, perm2, starts2, t2, inv, out);
}

// Round 6
// 590.793 us; speedup vs baseline: 1.4361x; 1.4361x over previous
//
#include <hip/hip_runtime.h>
#include <stdint.h>
#include <stddef.h>

#define D0 4096
#define D1 1024
#define NOUT 1000
#define NB 64

#define NCH0 2
#define CHSH0 11
#define NBK0 (33 * NCH0)        // 66
#define PSTRIDE0 4352           // >= 4096 + 66*3, multiple of 4 (16B-aligned rows)
#define SENT0 (4096u << 14)     // byte offset of zero row in w0T

#define NBK2 33                 // core 2: no chunk split (w2T is 4 MB, L2-resident)
#define PSTRIDE2 1124           // >= 1024 + 33*3, multiple of 4 (4496 B rows, 16B-aligned)
#define SENT2 (1024u << 12)     // byte offset of zero row in w2T

// ---------------------------------------------------------------------------
// Spike pattern for uniform spike coding, N in [0,32] -> 32-bit cycle mask.
// Matches jnp: spacing = 32.f/N (fp32), spike at c iff fmod(c, spacing) < 1.
// floor(c/spacing) < N always true for 0<N<32 (margin >= N/32 >> fp eps).
// ---------------------------------------------------------------------------
__device__ __forceinline__ uint32_t spike_pattern(int N) {
  if (N <= 0) return 0u;
  if (N >= 32) return 0xFFFFFFFFu;
  float spacing = 32.0f / (float)N;
  uint32_t m = 0;
  for (int c = 0; c < 32; ++c) {
    if (fmodf((float)c, spacing) < 1.0f) m |= (1u << c);
  }
  return m;
}

// ---------------------------------------------------------------------------
// Fused prep (same as R5):
//  blocks [0,64):   per-batch counting sort of core-0 inputs by key =
//                   33*chunk + N (chunk = j>>11), buckets padded to x4 with
//                   sentinel zero-row byte offsets; perm prescaled (j<<14).
//  block 64:        inverse output index + zero sentinel rows.
//  next 16384:      w0 transpose tiles -> w0T[j][o].
//  last 1024:       w2 transpose tiles -> w2T[j][o] (o >= 1000 zero-padded).
// Within-bucket order is atomic-nondeterministic: perturbs fp64 bucket sums
// only at ~1e-16 (absmax stayed 0 across R1-R5 with this property).
// ---------------------------------------------------------------------------
__global__ void prep_k(const float* __restrict__ w0, const float* __restrict__ w2,
                       const float* __restrict__ x, const int* __restrict__ idx0,
                       const int* __restrict__ idx_out,
                       float* __restrict__ w0T, float* __restrict__ w2T,
                       uint32_t* __restrict__ perm0, int* __restrict__ starts0,
                       int* __restrict__ inv) {
  __shared__ int keys[D0];
  __shared__ int hist[NBK0];
  __shared__ int base[NBK0 + 1];
  __shared__ int cursor[NBK0];
  __shared__ float tile[32][33];
  int bid = blockIdx.x;
  int tid = threadIdx.x;
  if (bid < NB) {
    int b = bid;
    for (int k = tid; k < NBK0; k += 256) hist[k] = 0;
    __syncthreads();
    for (int j = tid; j < D0; j += 256) {
      int N = (int)rintf(x[(size_t)b * D0 + idx0[j]] * 32.0f);  // round-half-even
      int k = (j >> CHSH0) * 33 + N;
      keys[j] = k;
      atomicAdd(&hist[k], 1);
    }
    __syncthreads();
    if (tid == 0) {
      int s = 0;
      for (int k = 0; k < NBK0; ++k) {
        base[k] = s; cursor[k] = s;
        s += hist[k];
        s = (s + 3) & ~3;           // pad bucket to multiple of 4
      }
      base[NBK0] = s;
    }
    __syncthreads();
    for (int k = tid; k <= NBK0; k += 256) starts0[b * (NBK0 + 1) + k] = base[k];
    uint32_t* pb = perm0 + (size_t)b * PSTRIDE0;
    for (int i = tid; i < PSTRIDE0; i += 256) pb[i] = SENT0;
    __syncthreads();
    for (int j = tid; j < D0; j += 256) {
      int pos = atomicAdd(&cursor[keys[j]], 1);
      pb[pos] = (uint32_t)j << 14;  // prescaled byte offset into w0T
    }
  } else if (bid == NB) {
    for (int o = tid; o < D1; o += 256) inv[o] = -1;
    __syncthreads();
    for (int r = tid; r < NOUT; r += 256) inv[idx_out[r]] = r;
    float* zr0 = w0T + (size_t)D0 * D0;
    for (int i = tid; i < D0; i += 256) zr0[i] = 0.0f;
    float* zr2 = w2T + (size_t)D1 * D1;
    for (int i = tid; i < D1; i += 256) zr2[i] = 0.0f;
  } else if (bid < NB + 1 + 16384) {
    int tb = bid - (NB + 1);
    int j0 = (tb & 127) * 32;
    int o0 = (tb >> 7) * 32;
    int tx = tid & 31, ty = tid >> 5;
    for (int r = ty; r < 32; r += 8)
      tile[r][tx] = w0[(size_t)(o0 + r) * D0 + j0 + tx];
    __syncthreads();
    for (int r = ty; r < 32; r += 8)
      w0T[(size_t)(j0 + r) * D0 + o0 + tx] = tile[tx][r];
  } else {
    int tb = bid - (NB + 1 + 16384);
    int j0 = (tb & 31) * 32;
    int o0 = (tb >> 5) * 32;
    int tx = tid & 31, ty = tid >> 5;
    for (int r = ty; r < 32; r += 8) {
      int o = o0 + r;
      tile[r][tx] = (o < NOUT) ? w2[(size_t)o * D1 + j0 + tx] : 0.0f;
    }
    __syncthreads();
    for (int r = ty; r < 32; r += 8)
      w2T[(size_t)(j0 + r) * D1 + o0 + tx] = tile[tx][r];
  }
}

// ---------------------------------------------------------------------------
// Core-0 LIF, fp64-exact, no atomics, no dynamic register indexing.
// Block = 64 o's x 4 key-waves: wave w handles keys [8w+1, 8w+8] over both
// j-chunks (chunk-major sweep -> L2-resident wt window). Per-thread bsum[8]
// is statically indexed (16 VGPRs — no scratch spill, the R5 bug). Segments
// are 4-aligned/4-sized (sentinel-padded): inner loop = uint4 perm loads +
// 8 independent gathers in flight; address = uniform byte offset + o*4.
// Waves write bsum to padded LDS (2-way bank aliasing = free), wave 0 does
// the pattern-scatter (fixed k-ascending order) + 32-step membrane scan.
// ---------------------------------------------------------------------------
__launch_bounds__(256, 4)
__global__ void lif0_k(const float* __restrict__ wt, const uint32_t* __restrict__ perm,
                       const int* __restrict__ starts, const float* __restrict__ thr_p,
                       int* __restrict__ cnt_out) {
  __shared__ uint32_t pat[33];
  __shared__ int stL[NBK0 + 1];
  __shared__ double cLDS[64][33];  // [o_local][key-1], +1 pad -> conflict-free
  int tid = threadIdx.x;
  int o_local = tid & 63;
  int wv = tid >> 6;               // wave id 0..3 (wave-uniform)
  int b = blockIdx.y;
  int o = blockIdx.x * 64 + o_local;
  if (tid < 33) pat[tid] = spike_pattern(tid);
  if (tid < NBK0 + 1) stL[tid] = starts[b * (NBK0 + 1) + tid];
  __syncthreads();

  const char* wtc = (const char*)wt;
  uint32_t o4 = (uint32_t)o * 4u;
  const uint32_t* permb = perm + (size_t)b * PSTRIDE0;

  double bsum[8];
#pragma unroll
  for (int k = 0; k < 8; ++k) bsum[k] = 0.0;

  for (int ch = 0; ch < NCH0; ++ch) {
#pragma unroll
    for (int kk = 0; kk < 8; ++kk) {
      int seg = ch * 33 + wv * 8 + kk + 1;
      int s = stL[seg], e = stL[seg + 1];
      if (s == e) continue;  // wave-uniform
      double a0 = 0.0, a1 = 0.0, a2 = 0.0, a3 = 0.0;
      int i = s;
      for (; i + 8 <= e; i += 8) {
        uint4 p0 = *(const uint4*)(permb + i);
        uint4 p1 = *(const uint4*)(permb + i + 4);
        float f0 = *(const float*)(wtc + (uint32_t)(p0.x + o4));
        float f1 = *(const float*)(wtc + (uint32_t)(p0.y + o4));
        float f2 = *(const float*)(wtc + (uint32_t)(p0.z + o4));
        float f3 = *(const float*)(wtc + (uint32_t)(p0.w + o4));
        float f4 = *(const float*)(wtc + (uint32_t)(p1.x + o4));
        float f5 = *(const float*)(wtc + (uint32_t)(p1.y + o4));
        float f6 = *(const float*)(wtc + (uint32_t)(p1.z + o4));
        float f7 = *(const float*)(wtc + (uint32_t)(p1.w + o4));
        a0 += (double)f0; a1 += (double)f1; a2 += (double)f2; a3 += (double)f3;
        a0 += (double)f4; a1 += (double)f5; a2 += (double)f6; a3 += (double)f7;
      }
      if (i < e) {  // exactly 4 (segments are multiples of 4)
        uint4 p0 = *(const uint4*)(permb + i);
        float f0 = *(const float*)(wtc + (uint32_t)(p0.x + o4));
        float f1 = *(const float*)(wtc + (uint32_t)(p0.y + o4));
        float f2 = *(const float*)(wtc + (uint32_t)(p0.z + o4));
        float f3 = *(const float*)(wtc + (uint32_t)(p0.w + o4));
        a0 += (double)f0; a1 += (double)f1; a2 += (double)f2; a3 += (double)f3;
      }
      bsum[kk] += (a0 + a1) + (a2 + a3);
    }
  }

#pragma unroll
  for (int kk = 0; kk < 8; ++kk)
    cLDS[o_local][wv * 8 + kk] = bsum[kk];
  __syncthreads();

  if (tid < 64) {
    double contrib[32];
#pragma unroll
    for (int t = 0; t < 32; ++t) contrib[t] = 0.0;
#pragma unroll
    for (int k = 1; k <= 32; ++k) {
      uint32_t m = pat[k];
      double v = cLDS[tid][k - 1];
#pragma unroll
      for (int t = 0; t < 32; ++t)
        contrib[t] += ((m >> t) & 1u) ? v : 0.0;
    }
    double th = (double)thr_p[0];
    double memb = 0.0;
    int cnt = 0;
#pragma unroll
    for (int t = 0; t < 32; ++t) {
      memb += contrib[t];
      if (memb > th) { memb -= th; ++cnt; }  // strict: threshold < memb
    }
    cnt_out[(size_t)b * D0 + blockIdx.x * 64 + tid] = cnt;
  }
}

// ---------------------------------------------------------------------------
// Core-2 prep: avg_pool2d on exact spike counts -> N1 = rint(cnt4/4) (exact:
// cnt4 in [0,128]; clip no-op), then padded counting sort into 33 buckets,
// perm prescaled (j<<12), sentinel = zero row of w2T.
// ---------------------------------------------------------------------------
__global__ void pool_sort_k(const int* __restrict__ k0, const int* __restrict__ idx1,
                            const int* __restrict__ idx2,
                            uint32_t* __restrict__ perm, int* __restrict__ starts) {
  __shared__ int Nls[D1];
  __shared__ int keys[D1];
  __shared__ int hist[NBK2];
  __shared__ int base[NBK2 + 1];
  __shared__ int cursor[NBK2];
  int b = blockIdx.x, tid = threadIdx.x;
  if (tid < NBK2) hist[tid] = 0;
  for (int i = tid; i < D1; i += 256) {
    int c = i >> 4, h2 = (i >> 2) & 3, w2v = i & 3;
    int cnt = 0;
#pragma unroll
    for (int dh = 0; dh < 2; ++dh)
#pragma unroll
      for (int dw = 0; dw < 2; ++dw) {
        int q = c * 64 + (2 * h2 + dh) * 8 + (2 * w2v + dw);
        cnt += k0[(size_t)b * D0 + idx1[q]];
      }
    Nls[i] = (int)rintf((float)cnt * 0.25f);
  }
  __syncthreads();
  for (int j = tid; j < D1; j += 256) {
    int k = Nls[idx2[j]];
    keys[j] = k;
    atomicAdd(&hist[k], 1);
  }
  __syncthreads();
  if (tid == 0) {
    int s = 0;
    for (int k = 0; k < NBK2; ++k) {
      base[k] = s; cursor[k] = s;
      s += hist[k];
      s = (s + 3) & ~3;
    }
    base[NBK2] = s;
  }
  __syncthreads();
  if (tid <= NBK2) starts[b * (NBK2 + 1) + tid] = base[tid];
  uint32_t* pb = perm + (size_t)b * PSTRIDE2;
  for (int i = tid; i < PSTRIDE2; i += 256) pb[i] = SENT2;
  __syncthreads();
  for (int j = tid; j < D1; j += 256) {
    int pos = atomicAdd(&cursor[keys[j]], 1);
    pb[pos] = (uint32_t)j << 12;
  }
}

// ---------------------------------------------------------------------------
// Core-2 LIF: same structure as lif0_k — 64 o's x 4 key-waves per block,
// grid (16, 64). bsum[8] static, LDS combine, wave-0 scan + inv-index write.
// ---------------------------------------------------------------------------
__launch_bounds__(256, 4)
__global__ void lif2_k(const float* __restrict__ wt, const uint32_t* __restrict__ perm,
                       const int* __restrict__ starts, const float* __restrict__ thr_p,
                       const int* __restrict__ inv, float* __restrict__ out) {
  __shared__ uint32_t pat[33];
  __shared__ int stL[NBK2 + 1];
  __shared__ double cLDS[64][33];
  int tid = threadIdx.x;
  int o_local = tid & 63;
  int wv = tid >> 6;
  int b = blockIdx.y;
  int o = blockIdx.x * 64 + o_local;
  if (tid < 33) pat[tid] = spike_pattern(tid);
  if (tid < NBK2 + 1) stL[tid] = starts[b * (NBK2 + 1) + tid];
  __syncthreads();

  const char* wtc = (const char*)wt;
  uint32_t o4 = (uint32_t)o * 4u;
  const uint32_t* permb = perm + (size_t)b * PSTRIDE2;

  double bsum[8];
#pragma unroll
  for (int k = 0; k < 8; ++k) bsum[k] = 0.0;

#pragma unroll
  for (int kk = 0; kk < 8; ++kk) {
    int seg = wv * 8 + kk + 1;
    int s = stL[seg], e = stL[seg + 1];
    if (s == e) continue;
    double a0 = 0.0, a1 = 0.0, a2 = 0.0, a3 = 0.0;
    int i = s;
    for (; i + 8 <= e; i += 8) {
      uint4 p0 = *(const uint4*)(permb + i);
      uint4 p1 = *(const uint4*)(permb + i + 4);
      float f0 = *(const float*)(wtc + (uint32_t)(p0.x + o4));
      float f1 = *(const float*)(wtc + (uint32_t)(p0.y + o4));
      float f2 = *(const float*)(wtc + (uint32_t)(p0.z + o4));
      float f3 = *(const float*)(wtc + (uint32_t)(p0.w + o4));
      float f4 = *(const float*)(wtc + (uint32_t)(p1.x + o4));
      float f5 = *(const float*)(wtc + (uint32_t)(p1.y + o4));
      float f6 = *(const float*)(wtc + (uint32_t)(p1.z + o4));
      float f7 = *(const float*)(wtc + (uint32_t)(p1.w + o4));
      a0 += (double)f0; a1 += (double)f1; a2 += (double)f2; a3 += (double)f3;
      a0 += (double)f4; a1 += (double)f5; a2 += (double)f6; a3 += (double)f7;
    }
    if (i < e) {
      uint4 p0 = *(const uint4*)(permb + i);
      float f0 = *(const float*)(wtc + (uint32_t)(p0.x + o4));
      float f1 = *(const float*)(wtc + (uint32_t)(p0.y + o4));
      float f2 = *(const float*)(wtc + (uint32_t)(p0.z + o4));
      float f3 = *(const float*)(wtc + (uint32_t)(p0.w + o4));
      a0 += (double)f0; a1 += (double)f1; a2 += (double)f2; a3 += (double)f3;
    }
    bsum[kk] += (a0 + a1) + (a2 + a3);
  }

#pragma unroll
  for (int kk = 0; kk < 8; ++kk)
    cLDS[o_local][wv * 8 + kk] = bsum[kk];
  __syncthreads();

  if (tid < 64) {
    double contrib[32];
#pragma unroll
    for (int t = 0; t < 32; ++t) contrib[t] = 0.0;
#pragma unroll
    for (int k = 1; k <= 32; ++k) {
      uint32_t m = pat[k];
      double v = cLDS[tid][k - 1];
#pragma unroll
      for (int t = 0; t < 32; ++t)
        contrib[t] += ((m >> t) & 1u) ? v : 0.0;
    }
    double th = (double)thr_p[0];
    double memb = 0.0;
    int cnt = 0;
#pragma unroll
    for (int t = 0; t < 32; ++t) {
      memb += contrib[t];
      if (memb > th) { memb -= th; ++cnt; }
    }
    int oo = blockIdx.x * 64 + tid;
    int r = inv[oo];
    if (r >= 0) out[(size_t)b * NOUT + r] = (float)cnt;
  }
}

// ---------------------------------------------------------------------------
extern "C" void kernel_launch(void* const* d_in, const int* in_sizes, int n_in,
                              void* d_out, int out_size, void* d_ws, size_t ws_size,
                              hipStream_t stream) {
  const float* x      = (const float*)d_in[0];
  const float* w0     = (const float*)d_in[1];
  const float* t0     = (const float*)d_in[2];
  const float* w2     = (const float*)d_in[3];
  const float* t2     = (const float*)d_in[4];
  const int*   idx0   = (const int*)d_in[5];
  const int*   idx1   = (const int*)d_in[6];
  const int*   idx2   = (const int*)d_in[7];
  const int*   idx_out= (const int*)d_in[8];
  float* out = (float*)d_out;

  char* ws = (char*)d_ws;
  float*    w0T     = (float*)ws;    ws += (size_t)(D0 + 1) * D0 * 4;  // +sentinel row
  float*    w2T     = (float*)ws;    ws += (size_t)(D1 + 1) * D1 * 4;  // +sentinel row
  uint32_t* perm0   = (uint32_t*)ws; ws += (size_t)NB * PSTRIDE0 * 4;
  uint32_t* perm2   = (uint32_t*)ws; ws += (size_t)NB * PSTRIDE2 * 4;
  int*      k0      = (int*)ws;      ws += (size_t)NB * D0 * 4;
  int*      starts0 = (int*)ws;      ws += (size_t)NB * (NBK0 + 1) * 4;
  int*      starts2 = (int*)ws;      ws += (size_t)NB * (NBK2 + 1) * 4;
  int*      inv     = (int*)ws;      ws += (size_t)D1 * 4;

  prep_k<<<NB + 1 + 16384 + 1024, 256, 0, stream>>>(w0, w2, x, idx0, idx_out,
                                                    w0T, w2T, perm0, starts0, inv);
  lif0_k<<<dim3(D0 / 64, NB), 256, 0, stream>>>(w0T, perm0, starts0, t0, k0);
  pool_sort_k<<<NB, 256, 0, stream>>>(k0, idx1, idx2, perm2, starts2);
  lif2_k<<<dim3(D1 / 64, NB), 256, 0, stream>>>(w2T, perm2, starts2, t2, inv, out);
}